// Round 1
// baseline (701.468 us; speedup 1.0000x reference)
//
#include <hip/hip_runtime.h>
#include <math.h>

#define R    116
#define R2   (116*116)
#define G    128
#define NN   (R*G)      // 14848 nodes
#define HID  64
#define EDIM 5
#define INCH 116
#define EMBD 16

__device__ __forceinline__ float waveReduceSum(float v) {
#pragma unroll
    for (int m = 32; m >= 1; m >>= 1) v += __shfl_xor(v, m, 64);
    return v;
}

// ---------------- encode: h = relu([x, emb[gid]] @ W + b) ----------------
__global__ __launch_bounds__(64) void k_encode(
    const float* __restrict__ x, const float* __restrict__ emb,
    const int* __restrict__ group_ids,
    const float* __restrict__ W, const float* __restrict__ b,
    float* __restrict__ h) {
    int n = blockIdx.x;
    int c = threadIdx.x;
    __shared__ float xin[INCH + EMBD];
    for (int k = c; k < INCH; k += 64) xin[k] = x[n*INCH + k];
    if (c < EMBD) xin[INCH + c] = emb[group_ids[n]*EMBD + c];
    __syncthreads();
    float acc = b[c];
#pragma unroll 4
    for (int k = 0; k < INCH + EMBD; ++k) acc = fmaf(xin[k], W[k*HID + c], acc);
    h[n*HID + c] = fmaxf(acc, 0.f);
}

// ---------------- batchnorm stats (two-stage, deterministic) ----------------
__global__ __launch_bounds__(256) void k_stats_partial(
    const float* __restrict__ h, float* __restrict__ partials) {
    int b = blockIdx.x;                 // NN/64 = 232 blocks, 64 rows each
    int tid = threadIdx.x;
    int c = tid & 63, r0 = tid >> 6;
    float s = 0.f, s2 = 0.f;
    int row0 = b*64;
#pragma unroll
    for (int k = 0; k < 16; ++k) {
        float v = h[(row0 + r0 + 4*k)*HID + c];
        s += v; s2 += v*v;
    }
    __shared__ float ls[256], l2[256];
    ls[tid] = s; l2[tid] = s2;
    __syncthreads();
    if (tid < 64) {
        s  = ls[tid] + ls[tid+64] + ls[tid+128] + ls[tid+192];
        s2 = l2[tid] + l2[tid+64] + l2[tid+128] + l2[tid+192];
        partials[b*128 + tid]      = s;
        partials[b*128 + 64 + tid] = s2;
    }
}

__global__ __launch_bounds__(64) void k_stats_final(
    const float* __restrict__ partials, const float* __restrict__ gam,
    const float* __restrict__ bet, float* __restrict__ stats) {
    int c = threadIdx.x;
    float s = 0.f, s2 = 0.f;
    for (int b = 0; b < NN/64; ++b) {
        s  += partials[b*128 + c];
        s2 += partials[b*128 + 64 + c];
    }
    float mu  = s / (float)NN;
    float var = s2 / (float)NN - mu*mu;
    float rs  = rsqrtf(var + 1e-5f);
    float sc  = rs * gam[c];
    stats[c]      = sc;
    stats[64 + c] = bet[c] - mu*sc;
}

__global__ __launch_bounds__(256) void k_bn(
    float* __restrict__ h, const float* __restrict__ stats) {
    int i = blockIdx.x*256 + threadIdx.x;
    if (i < NN*HID) {
        int c = i & 63;
        h[i] = fmaf(h[i], stats[c], stats[64 + c]);
    }
}

// ---------------- GINE: agg + residual + MLP, fused ----------------
__global__ __launch_bounds__(64) void k_gine(
    const float* __restrict__ h, const float* __restrict__ ea,
    const float* __restrict__ We, const float* __restrict__ be,
    const float* __restrict__ W1, const float* __restrict__ b1,
    const float* __restrict__ W2, const float* __restrict__ b2,
    float* __restrict__ hout) {
    int b = blockIdx.x;
    int g = b / R, j = b - g*R;
    int c = threadIdx.x;
    float w0 = We[c], w1 = We[64+c], w2 = We[128+c], w3 = We[192+c], w4 = We[256+c];
    float bec = be[c];
    float agg = 0.f;
    int ebase = (g*R2 + j)*EDIM;
    int hbase = g*R*HID;
    for (int i = 0; i < R; ++i) {
        int eo = ebase + i*(R*EDIM);
        float eam = (c < EDIM) ? ea[eo + c] : 0.f;
        float e0 = __shfl(eam,0,64), e1 = __shfl(eam,1,64), e2 = __shfl(eam,2,64),
              e3 = __shfl(eam,3,64), e4 = __shfl(eam,4,64);
        float ew = bec + e0*w0 + e1*w1 + e2*w2 + e3*w3 + e4*w4;
        float v  = h[hbase + i*HID + c] + ew;
        agg += fmaxf(v, 0.f);
    }
    float h1 = h[b*HID + c] + agg;
    __shared__ float t1[HID], t2[HID];
    t1[c] = h1;
    __syncthreads();
    float acc = b1[c];
#pragma unroll 8
    for (int k = 0; k < HID; ++k) acc = fmaf(t1[k], W1[k*HID + c], acc);
    t2[c] = fmaxf(acc, 0.f);
    __syncthreads();
    float acc2 = b2[c];
#pragma unroll 8
    for (int k = 0; k < HID; ++k) acc2 = fmaf(t2[k], W2[k*HID + c], acc2);
    hout[b*HID + c] = fmaxf(acc2, 0.f);
}

// ---------------- GAT: xl/xr projections ----------------
__global__ __launch_bounds__(64) void k_xlxr(
    const float* __restrict__ h,
    const float* __restrict__ Wl, const float* __restrict__ bl,
    const float* __restrict__ Wr, const float* __restrict__ br,
    float* __restrict__ xl, float* __restrict__ xr) {
    int n = blockIdx.x, c = threadIdx.x;
    __shared__ float hr[HID];
    hr[c] = h[n*HID + c];
    __syncthreads();
    float aL = bl[c], aR = br[c];
#pragma unroll 8
    for (int k = 0; k < HID; ++k) {
        aL = fmaf(hr[k], Wl[k*HID + c], aL);
        aR = fmaf(hr[k], Wr[k*HID + c], aR);
    }
    xl[n*HID + c] = aL;
    xr[n*HID + c] = aR;
}

// ---------------- GAT: scores + softmax + aggregation per (g, dst) ----------------
__global__ __launch_bounds__(64) void k_gat(
    const float* __restrict__ xl, const float* __restrict__ xr,
    const float* __restrict__ ea, const float* __restrict__ We,
    const float* __restrict__ att, const float* __restrict__ bias,
    float* __restrict__ hout) {
    int b = blockIdx.x;
    int g = b / R, j = b - g*R;
    int c = threadIdx.x;
    float w0 = We[c], w1 = We[64+c], w2 = We[128+c], w3 = We[192+c], w4 = We[256+c];
    float xrc  = xr[b*HID + c];
    float attc = att[c];
    __shared__ float sc[R];
    float smax = -1e30f;
    int ebase = (g*R2 + j)*EDIM;
    int hbase = g*R*HID;
    for (int i = 0; i < R; ++i) {
        int eo = ebase + i*(R*EDIM);
        float eam = (c < EDIM) ? ea[eo + c] : 0.f;
        float e0 = __shfl(eam,0,64), e1 = __shfl(eam,1,64), e2 = __shfl(eam,2,64),
              e3 = __shfl(eam,3,64), e4 = __shfl(eam,4,64);
        float v = xl[hbase + i*HID + c] + xrc + e0*w0 + e1*w1 + e2*w2 + e3*w3 + e4*w4;
        v = (v > 0.f) ? v : 0.2f*v;
        float p = waveReduceSum(v * attc);
        if (c == 0) sc[i] = p;
        smax = fmaxf(smax, p);
    }
    __syncthreads();
    float loc = 0.f;
    for (int i = c; i < R; i += 64) {
        float exv = __expf(sc[i] - smax);
        sc[i] = exv;
        loc += exv;
    }
    float denom = waveReduceSum(loc) + 1e-16f;
    __syncthreads();
    float outv = 0.f;
    for (int i = 0; i < R; ++i) outv = fmaf(sc[i], xl[hbase + i*HID + c], outv);
    hout[b*HID + c] = fmaxf(outv / denom + bias[c], 0.f);
}

// ---------------- pooling ----------------
__global__ __launch_bounds__(64) void k_pool_score(
    const float* __restrict__ h, const float* __restrict__ W1,
    const float* __restrict__ b1, const float* __restrict__ w2,
    float* __restrict__ scores) {
    int n = blockIdx.x, c = threadIdx.x;
    __shared__ float hr[HID];
    hr[c] = h[n*HID + c];
    __syncthreads();
    float acc = b1[c];
#pragma unroll 8
    for (int k = 0; k < HID; ++k) acc = fmaf(hr[k], W1[k*HID + c], acc);
    float p = tanhf(acc) * w2[c];
    p = waveReduceSum(p);
    if (c == 0) scores[n] = p;
}

__global__ __launch_bounds__(1024) void k_pool_reduce(
    const float* __restrict__ scores, float* __restrict__ ms) {
    __shared__ float red[1024];
    int tid = threadIdx.x;
    float m = -1e30f;
    for (int i = tid; i < NN; i += 1024) m = fmaxf(m, scores[i]);
    red[tid] = m;
    __syncthreads();
    for (int s = 512; s > 0; s >>= 1) {
        if (tid < s) red[tid] = fmaxf(red[tid], red[tid+s]);
        __syncthreads();
    }
    float mx = red[0];
    __syncthreads();
    float sum = 0.f;
    for (int i = tid; i < NN; i += 1024) sum += __expf(scores[i] - mx);
    red[tid] = sum;
    __syncthreads();
    for (int s = 512; s > 0; s >>= 1) {
        if (tid < s) red[tid] += red[tid+s];
        __syncthreads();
    }
    if (tid == 0) { ms[0] = mx; ms[1] = red[0]; }
}

__global__ __launch_bounds__(64) void k_pool_final(
    const float* __restrict__ h, const float* __restrict__ scores,
    const float* __restrict__ ms,
    const float* __restrict__ lin1W, const float* __restrict__ lin1b,
    const float* __restrict__ lin2W, const float* __restrict__ lin2b,
    float* __restrict__ out) {
    int g = blockIdx.x, c = threadIdx.x;
    float mx = ms[0], inv = 1.f / ms[1];
    float pc = 0.f;
    int nb = g*R;
    for (int r = 0; r < R; ++r) {
        float wv = __expf(scores[nb + r] - mx) * inv;
        pc = fmaf(h[(nb + r)*HID + c], wv, pc);
    }
    __shared__ float pl[HID];
    __shared__ float t[INCH];
    pl[c] = pc;
    __syncthreads();
    for (int k = c; k < INCH; k += 64) {
        float acc = lin1b[k];
#pragma unroll 8
        for (int q = 0; q < HID; ++q) acc = fmaf(pl[q], lin1W[q*INCH + k], acc);
        t[k] = fmaxf(acc, 0.f);
    }
    __syncthreads();
    if (c < 2) {
        float o = lin2b[c];
        for (int k = 0; k < INCH; ++k) o = fmaf(t[k], lin2W[k*2 + c], o);
        out[g*2 + c] = o;
    }
}

extern "C" void kernel_launch(void* const* d_in, const int* in_sizes, int n_in,
                              void* d_out, int out_size, void* d_ws, size_t ws_size,
                              hipStream_t stream) {
    (void)in_sizes; (void)n_in; (void)out_size; (void)ws_size;
    const float* x        = (const float*)d_in[0];
    const float* edge_attr= (const float*)d_in[1];
    const float* emb      = (const float*)d_in[2];
    const float* enc_W    = (const float*)d_in[3];
    const float* enc_b    = (const float*)d_in[4];
    const float* bn_g     = (const float*)d_in[5];
    const float* bn_b     = (const float*)d_in[6];
    const float* gine_We  = (const float*)d_in[7];
    const float* gine_be  = (const float*)d_in[8];
    const float* gine_W1  = (const float*)d_in[9];
    const float* gine_b1  = (const float*)d_in[10];
    const float* gine_W2  = (const float*)d_in[11];
    const float* gine_b2  = (const float*)d_in[12];
    const float* gat_Wl   = (const float*)d_in[13];
    const float* gat_bl   = (const float*)d_in[14];
    const float* gat_Wr   = (const float*)d_in[15];
    const float* gat_br   = (const float*)d_in[16];
    const float* gat_att  = (const float*)d_in[17];
    const float* gat_We   = (const float*)d_in[18];
    const float* gat_bias = (const float*)d_in[19];
    const float* pool_W1  = (const float*)d_in[20];
    const float* pool_b1  = (const float*)d_in[21];
    const float* pool_w2  = (const float*)d_in[22];
    const float* lin1_W   = (const float*)d_in[23];
    const float* lin1_b   = (const float*)d_in[24];
    const float* lin2_W   = (const float*)d_in[25];
    const float* lin2_b   = (const float*)d_in[26];
    const int*   group_ids= (const int*)d_in[29];
    float* out = (float*)d_out;

    float* w = (float*)d_ws;
    float* hA       = w;                         // NN*HID
    float* hB       = hA + NN*HID;               // NN*HID
    float* xl       = hB + NN*HID;               // NN*HID
    float* xr       = xl + NN*HID;               // NN*HID
    float* scores   = xr + NN*HID;               // NN
    float* partials = scores + NN;               // (NN/64)*128
    float* stats    = partials + (NN/64)*128;    // 128
    float* pms      = stats + 128;               // 2

    k_encode<<<NN, 64, 0, stream>>>(x, emb, group_ids, enc_W, enc_b, hA);
    k_stats_partial<<<NN/64, 256, 0, stream>>>(hA, partials);
    k_stats_final<<<1, 64, 0, stream>>>(partials, bn_g, bn_b, stats);
    k_bn<<<(NN*HID + 255)/256, 256, 0, stream>>>(hA, stats);
    k_gine<<<NN, 64, 0, stream>>>(hA, edge_attr, gine_We, gine_be,
                                  gine_W1, gine_b1, gine_W2, gine_b2, hB);
    // GAT layer 0: hB -> hA
    k_xlxr<<<NN, 64, 0, stream>>>(hB, gat_Wl, gat_bl, gat_Wr, gat_br, xl, xr);
    k_gat<<<NN, 64, 0, stream>>>(xl, xr, edge_attr, gat_We, gat_att, gat_bias, hA);
    // GAT layer 1: hA -> hB
    k_xlxr<<<NN, 64, 0, stream>>>(hA, gat_Wl + HID*HID, gat_bl + HID,
                                  gat_Wr + HID*HID, gat_br + HID, xl, xr);
    k_gat<<<NN, 64, 0, stream>>>(xl, xr, edge_attr, gat_We + EDIM*HID,
                                 gat_att + HID, gat_bias + HID, hB);
    // pooling + head
    k_pool_score<<<NN, 64, 0, stream>>>(hB, pool_W1, pool_b1, pool_w2, scores);
    k_pool_reduce<<<1, 1024, 0, stream>>>(scores, pms);
    k_pool_final<<<G, 64, 0, stream>>>(hB, scores, pms, lin1_W, lin1_b,
                                       lin2_W, lin2_b, out);
}

// Round 3
// 355.623 us; speedup vs baseline: 1.9725x; 1.9725x over previous
//
#include <hip/hip_runtime.h>
#include <math.h>

#define R    116
#define R2   (116*116)
#define G    128
#define NN   (R*G)      // 14848 nodes
#define HID  64
#define EDIM 5
#define INCH 116
#define EMBD 16
#define CH   15         // dst chunk per block; 8 chunks cover 116

__device__ __forceinline__ float waveReduceSum(float v) {
#pragma unroll
    for (int m = 32; m >= 1; m >>= 1) v += __shfl_xor(v, m, 64);
    return v;
}

// ---------------- encode: h = relu([x, emb[gid]] @ W + b) ----------------
__global__ __launch_bounds__(64) void k_encode(
    const float* __restrict__ x, const float* __restrict__ emb,
    const int* __restrict__ group_ids,
    const float* __restrict__ W, const float* __restrict__ b,
    float* __restrict__ h) {
    int n = blockIdx.x;
    int c = threadIdx.x;
    __shared__ float xin[INCH + EMBD];
    for (int k = c; k < INCH; k += 64) xin[k] = x[n*INCH + k];
    if (c < EMBD) xin[INCH + c] = emb[group_ids[n]*EMBD + c];
    __syncthreads();
    float acc = b[c];
#pragma unroll 4
    for (int k = 0; k < INCH + EMBD; ++k) acc = fmaf(xin[k], W[k*HID + c], acc);
    h[n*HID + c] = fmaxf(acc, 0.f);
}

// ---------------- batchnorm stats (two-stage, deterministic) ----------------
__global__ __launch_bounds__(256) void k_stats_partial(
    const float* __restrict__ h, float* __restrict__ partials) {
    int b = blockIdx.x;                 // NN/64 = 232 blocks, 64 rows each
    int tid = threadIdx.x;
    int c = tid & 63, r0 = tid >> 6;
    float s = 0.f, s2 = 0.f;
    int row0 = b*64;
#pragma unroll
    for (int k = 0; k < 16; ++k) {
        float v = h[(row0 + r0 + 4*k)*HID + c];
        s += v; s2 += v*v;
    }
    __shared__ float ls[256], l2[256];
    ls[tid] = s; l2[tid] = s2;
    __syncthreads();
    if (tid < 64) {
        s  = ls[tid] + ls[tid+64] + ls[tid+128] + ls[tid+192];
        s2 = l2[tid] + l2[tid+64] + l2[tid+128] + l2[tid+192];
        partials[b*128 + tid]      = s;
        partials[b*128 + 64 + tid] = s2;
    }
}

__global__ __launch_bounds__(64) void k_stats_final(
    const float* __restrict__ partials, const float* __restrict__ gam,
    const float* __restrict__ bet, float* __restrict__ stats) {
    int c = threadIdx.x;
    float s = 0.f, s2 = 0.f;
    for (int b = 0; b < NN/64; ++b) {
        s  += partials[b*128 + c];
        s2 += partials[b*128 + 64 + c];
    }
    float mu  = s / (float)NN;
    float var = s2 / (float)NN - mu*mu;
    float rs  = rsqrtf(var + 1e-5f);
    float sc  = rs * gam[c];
    stats[c]      = sc;
    stats[64 + c] = bet[c] - mu*sc;
}

__global__ __launch_bounds__(256) void k_bn(
    float* __restrict__ h, const float* __restrict__ stats) {
    int i = blockIdx.x*256 + threadIdx.x;
    if (i < NN*HID) {
        int c = i & 63;
        h[i] = fmaf(h[i], stats[c], stats[64 + c]);
    }
}

// ---------------- GINE: chunked, LDS-staged h, strip-loaded edge attrs --------
__global__ __launch_bounds__(256) void k_gine(
    const float* __restrict__ h, const float* __restrict__ ea,
    const float* __restrict__ We, const float* __restrict__ be,
    const float* __restrict__ W1, const float* __restrict__ b1,
    const float* __restrict__ W2, const float* __restrict__ b2,
    float* __restrict__ hout) {
    int b = blockIdx.x;
    int g = b >> 3, chunk = b & 7;
    int j0 = chunk * CH;
    int jcnt = min(CH, R - j0);
    int tid = threadIdx.x, w = tid >> 6, lane = tid & 63;
    __shared__ float hs[R][65];
    __shared__ float t1s[4][64];
    int hbase = g*R*HID;
    for (int idx = tid; idx < R*HID; idx += 256)
        hs[idx>>6][idx&63] = h[hbase + idx];
    __syncthreads();
    float w0 = We[lane], w1 = We[64+lane], w2v = We[128+lane],
          w3 = We[192+lane], w4 = We[256+lane];
    float bec = be[lane];
    for (int jj = w; jj < jcnt; jj += 4) {
        int j = j0 + jj;
        const float* eap = ea + ((size_t)(g*R)*R + j)*EDIM;
        float agg = 0.f;
        for (int i0 = 0; i0 < R; i0 += 64) {
            int imax = min(64, R - i0);
            float v0=0.f, v1=0.f, v2=0.f, v3=0.f, v4=0.f;
            if (lane < imax) {
                size_t eo = (size_t)(i0 + lane)*R*EDIM;
                v0 = eap[eo+0]; v1 = eap[eo+1]; v2 = eap[eo+2];
                v3 = eap[eo+3]; v4 = eap[eo+4];
            }
            for (int ii = 0; ii < imax; ++ii) {
                float e0 = __shfl(v0, ii, 64), e1 = __shfl(v1, ii, 64),
                      e2 = __shfl(v2, ii, 64), e3 = __shfl(v3, ii, 64),
                      e4 = __shfl(v4, ii, 64);
                float ew = bec + e0*w0 + e1*w1 + e2*w2v + e3*w3 + e4*w4;
                agg += fmaxf(hs[i0+ii][lane] + ew, 0.f);
            }
        }
        float h1 = hs[j][lane] + agg;
        t1s[w][lane] = h1;
        float acc = b1[lane];
#pragma unroll 8
        for (int k = 0; k < HID; ++k) acc = fmaf(t1s[w][k], W1[k*HID + lane], acc);
        float t2 = fmaxf(acc, 0.f);
        t1s[w][lane] = t2;
        float acc2 = b2[lane];
#pragma unroll 8
        for (int k = 0; k < HID; ++k) acc2 = fmaf(t1s[w][k], W2[k*HID + lane], acc2);
        hout[hbase + j*HID + lane] = fmaxf(acc2, 0.f);
    }
}

// ---------------- GAT: xl/xr projections ----------------
__global__ __launch_bounds__(64) void k_xlxr(
    const float* __restrict__ h,
    const float* __restrict__ Wl, const float* __restrict__ bl,
    const float* __restrict__ Wr, const float* __restrict__ br,
    float* __restrict__ xl, float* __restrict__ xr) {
    int n = blockIdx.x, c = threadIdx.x;
    __shared__ float hr[HID];
    hr[c] = h[n*HID + c];
    __syncthreads();
    float aL = bl[c], aR = br[c];
#pragma unroll 8
    for (int k = 0; k < HID; ++k) {
        aL = fmaf(hr[k], Wl[k*HID + c], aL);
        aR = fmaf(hr[k], Wr[k*HID + c], aR);
    }
    xl[n*HID + c] = aL;
    xr[n*HID + c] = aR;
}

// ---------------- GAT: lane=src score phase, per-dst softmax, lane=ch agg -----
__global__ __launch_bounds__(256) void k_gat(
    const float* __restrict__ xl, const float* __restrict__ xr,
    const float* __restrict__ ea, const float* __restrict__ We,
    const float* __restrict__ att, const float* __restrict__ bias,
    float* __restrict__ hout) {
    int b = blockIdx.x;
    int g = b >> 3, chunk = b & 7;
    int j0 = chunk * CH;
    int jcnt = min(CH, R - j0);
    int tid = threadIdx.x, w = tid >> 6, lane = tid & 63;
    __shared__ float xls[128][65];     // rows 116..127 unused (read-masked)
    __shared__ float xrs[CH][65];
    __shared__ float att_s[64], bias_s[64];
    __shared__ float we_s[5][64];
    __shared__ float ps[4][120];
    int hbase = g*R*HID;
    for (int idx = tid; idx < R*HID; idx += 256)
        xls[idx>>6][idx&63] = xl[hbase + idx];
    for (int idx = tid; idx < jcnt*HID; idx += 256)
        xrs[idx>>6][idx&63] = xr[hbase + j0*HID + idx];
    if (tid < 64) { att_s[tid] = att[tid]; bias_s[tid] = bias[tid]; }
    for (int idx = tid; idx < EDIM*HID; idx += 256)      // FIX: full 320 elems
        ((float*)we_s)[idx] = We[idx];
    __syncthreads();

    bool vB = lane < (R - 64);         // pass B covers sources 64..115
    for (int jj = w; jj < jcnt; jj += 4) {
        int j = j0 + jj;
        const float* eap = ea + ((size_t)(g*R)*R + j)*EDIM;
        float a0 = eap[(size_t)lane*R*EDIM + 0];
        float a1 = eap[(size_t)lane*R*EDIM + 1];
        float a2 = eap[(size_t)lane*R*EDIM + 2];
        float a3 = eap[(size_t)lane*R*EDIM + 3];
        float a4 = eap[(size_t)lane*R*EDIM + 4];
        float b0=0.f, b1v=0.f, b2v=0.f, b3=0.f, b4=0.f;
        if (vB) {
            size_t eo = (size_t)(64 + lane)*R*EDIM;
            b0 = eap[eo+0]; b1v = eap[eo+1]; b2v = eap[eo+2];
            b3 = eap[eo+3]; b4 = eap[eo+4];
        }
        float accA = 0.f, accB = 0.f;
#pragma unroll 8
        for (int c = 0; c < HID; ++c) {
            float u  = xrs[jj][c];
            float g0 = we_s[0][c], g1 = we_s[1][c], g2 = we_s[2][c],
                  g3 = we_s[3][c], g4 = we_s[4][c];
            float zA = xls[lane][c]    + u + a0*g0 + a1*g1 + a2*g2 + a3*g3 + a4*g4;
            float zB = xls[64+lane][c] + u + b0*g0 + b1v*g1 + b2v*g2 + b3*g3 + b4*g4;
            zA = fmaxf(zA, 0.f) + 0.2f*fminf(zA, 0.f);
            zB = fmaxf(zB, 0.f) + 0.2f*fminf(zB, 0.f);
            float at = att_s[c];
            accA = fmaf(zA, at, accA);
            accB = fmaf(zB, at, accB);
        }
        float sA = accA;
        float sB = vB ? accB : -1e30f;
        float m = fmaxf(sA, sB);
#pragma unroll
        for (int msk = 32; msk >= 1; msk >>= 1) m = fmaxf(m, __shfl_xor(m, msk, 64));
        float eA = __expf(sA - m);
        float eB = vB ? __expf(sB - m) : 0.f;
        float s = eA + eB;
#pragma unroll
        for (int msk = 32; msk >= 1; msk >>= 1) s += __shfl_xor(s, msk, 64);
        float inv = 1.f / (s + 1e-16f);
        ps[w][lane] = eA * inv;
        if (vB) ps[w][64 + lane] = eB * inv;
        // same-wave LDS produce->consume; no barrier needed
        float o = 0.f;
#pragma unroll 4
        for (int i = 0; i < R; ++i) o = fmaf(ps[w][i], xls[i][lane], o);
        hout[hbase + j*HID + lane] = fmaxf(o + bias_s[lane], 0.f);
    }
}

// ---------------- pooling ----------------
__global__ __launch_bounds__(64) void k_pool_score(
    const float* __restrict__ h, const float* __restrict__ W1,
    const float* __restrict__ b1, const float* __restrict__ w2,
    float* __restrict__ scores) {
    int n = blockIdx.x, c = threadIdx.x;
    __shared__ float hr[HID];
    hr[c] = h[n*HID + c];
    __syncthreads();
    float acc = b1[c];
#pragma unroll 8
    for (int k = 0; k < HID; ++k) acc = fmaf(hr[k], W1[k*HID + c], acc);
    float p = tanhf(acc) * w2[c];
    p = waveReduceSum(p);
    if (c == 0) scores[n] = p;
}

__global__ __launch_bounds__(1024) void k_pool_reduce(
    const float* __restrict__ scores, float* __restrict__ ms) {
    __shared__ float red[1024];
    int tid = threadIdx.x;
    float m = -1e30f;
    for (int i = tid; i < NN; i += 1024) m = fmaxf(m, scores[i]);
    red[tid] = m;
    __syncthreads();
    for (int s = 512; s > 0; s >>= 1) {
        if (tid < s) red[tid] = fmaxf(red[tid], red[tid+s]);
        __syncthreads();
    }
    float mx = red[0];
    __syncthreads();
    float sum = 0.f;
    for (int i = tid; i < NN; i += 1024) sum += __expf(scores[i] - mx);
    red[tid] = sum;
    __syncthreads();
    for (int s = 512; s > 0; s >>= 1) {
        if (tid < s) red[tid] += red[tid+s];
        __syncthreads();
    }
    if (tid == 0) { ms[0] = mx; ms[1] = red[0]; }
}

__global__ __launch_bounds__(64) void k_pool_final(
    const float* __restrict__ h, const float* __restrict__ scores,
    const float* __restrict__ ms,
    const float* __restrict__ lin1W, const float* __restrict__ lin1b,
    const float* __restrict__ lin2W, const float* __restrict__ lin2b,
    float* __restrict__ out) {
    int g = blockIdx.x, c = threadIdx.x;
    float mx = ms[0], inv = 1.f / ms[1];
    float pc = 0.f;
    int nb = g*R;
    for (int r = 0; r < R; ++r) {
        float wv = __expf(scores[nb + r] - mx) * inv;
        pc = fmaf(h[(nb + r)*HID + c], wv, pc);
    }
    __shared__ float pl[HID];
    __shared__ float t[INCH];
    pl[c] = pc;
    __syncthreads();
    for (int k = c; k < INCH; k += 64) {
        float acc = lin1b[k];
#pragma unroll 8
        for (int q = 0; q < HID; ++q) acc = fmaf(pl[q], lin1W[q*INCH + k], acc);
        t[k] = fmaxf(acc, 0.f);
    }
    __syncthreads();
    if (c < 2) {
        float o = lin2b[c];
        for (int k = 0; k < INCH; ++k) o = fmaf(t[k], lin2W[k*2 + c], o);
        out[g*2 + c] = o;
    }
}

extern "C" void kernel_launch(void* const* d_in, const int* in_sizes, int n_in,
                              void* d_out, int out_size, void* d_ws, size_t ws_size,
                              hipStream_t stream) {
    (void)in_sizes; (void)n_in; (void)out_size; (void)ws_size;
    const float* x        = (const float*)d_in[0];
    const float* edge_attr= (const float*)d_in[1];
    const float* emb      = (const float*)d_in[2];
    const float* enc_W    = (const float*)d_in[3];
    const float* enc_b    = (const float*)d_in[4];
    const float* bn_g     = (const float*)d_in[5];
    const float* bn_b     = (const float*)d_in[6];
    const float* gine_We  = (const float*)d_in[7];
    const float* gine_be  = (const float*)d_in[8];
    const float* gine_W1  = (const float*)d_in[9];
    const float* gine_b1  = (const float*)d_in[10];
    const float* gine_W2  = (const float*)d_in[11];
    const float* gine_b2  = (const float*)d_in[12];
    const float* gat_Wl   = (const float*)d_in[13];
    const float* gat_bl   = (const float*)d_in[14];
    const float* gat_Wr   = (const float*)d_in[15];
    const float* gat_br   = (const float*)d_in[16];
    const float* gat_att  = (const float*)d_in[17];
    const float* gat_We   = (const float*)d_in[18];
    const float* gat_bias = (const float*)d_in[19];
    const float* pool_W1  = (const float*)d_in[20];
    const float* pool_b1  = (const float*)d_in[21];
    const float* pool_w2  = (const float*)d_in[22];
    const float* lin1_W   = (const float*)d_in[23];
    const float* lin1_b   = (const float*)d_in[24];
    const float* lin2_W   = (const float*)d_in[25];
    const float* lin2_b   = (const float*)d_in[26];
    const int*   group_ids= (const int*)d_in[29];
    float* out = (float*)d_out;

    float* w = (float*)d_ws;
    float* hA       = w;                         // NN*HID
    float* hB       = hA + NN*HID;               // NN*HID
    float* xl       = hB + NN*HID;               // NN*HID
    float* xr       = xl + NN*HID;               // NN*HID
    float* scores   = xr + NN*HID;               // NN
    float* partials = scores + NN;               // (NN/64)*128
    float* stats    = partials + (NN/64)*128;    // 128
    float* pms      = stats + 128;               // 2

    k_encode<<<NN, 64, 0, stream>>>(x, emb, group_ids, enc_W, enc_b, hA);
    k_stats_partial<<<NN/64, 256, 0, stream>>>(hA, partials);
    k_stats_final<<<1, 64, 0, stream>>>(partials, bn_g, bn_b, stats);
    k_bn<<<(NN*HID + 255)/256, 256, 0, stream>>>(hA, stats);
    k_gine<<<G*8, 256, 0, stream>>>(hA, edge_attr, gine_We, gine_be,
                                    gine_W1, gine_b1, gine_W2, gine_b2, hB);
    // GAT layer 0: hB -> hA
    k_xlxr<<<NN, 64, 0, stream>>>(hB, gat_Wl, gat_bl, gat_Wr, gat_br, xl, xr);
    k_gat<<<G*8, 256, 0, stream>>>(xl, xr, edge_attr, gat_We, gat_att, gat_bias, hA);
    // GAT layer 1: hA -> hB
    k_xlxr<<<NN, 64, 0, stream>>>(hA, gat_Wl + HID*HID, gat_bl + HID,
                                  gat_Wr + HID*HID, gat_br + HID, xl, xr);
    k_gat<<<G*8, 256, 0, stream>>>(xl, xr, edge_attr, gat_We + EDIM*HID,
                                   gat_att + HID, gat_bias + HID, hB);
    // pooling + head
    k_pool_score<<<NN, 64, 0, stream>>>(hB, pool_W1, pool_b1, pool_w2, scores);
    k_pool_reduce<<<1, 1024, 0, stream>>>(scores, pms);
    k_pool_final<<<G, 64, 0, stream>>>(hB, scores, pms, lin1_W, lin1_b,
                                       lin2_W, lin2_b, out);
}

// Round 4
// 311.837 us; speedup vs baseline: 2.2495x; 1.1404x over previous
//
#include <hip/hip_runtime.h>
#include <math.h>

#define R    116
#define R2   (116*116)
#define G    128
#define NN   (R*G)      // 14848 nodes
#define HID  64
#define EDIM 5
#define INCH 116
#define EMBD 16

__device__ __forceinline__ float waveReduceSum(float v) {
#pragma unroll
    for (int m = 32; m >= 1; m >>= 1) v += __shfl_xor(v, m, 64);
    return v;
}

// ---------------- edge-attr transpose: eat[g][j][i][e] = ea[g][i][j][e] -------
__global__ __launch_bounds__(256) void k_etr(
    const float* __restrict__ ea, float* __restrict__ eat) {
    int b = blockIdx.x;
    int g = b >> 4;
    int t = b & 15;
    int i0 = (t >> 2) << 5, j0 = (t & 3) << 5;
    int ni = min(32, R - i0), nj = min(32, R - j0);
    __shared__ float tile[32][165];
    const float* src = ea + ((size_t)(g*R + i0)*R + j0)*EDIM;
    int tot = ni * nj * EDIM;
    for (int idx = threadIdx.x; idx < tot; idx += 256) {
        int ii = idx / (nj*EDIM);
        int rem = idx - ii*(nj*EDIM);
        tile[ii][rem] = src[(size_t)ii*R*EDIM + rem];
    }
    __syncthreads();
    float* dst = eat + ((size_t)(g*R + j0)*R + i0)*EDIM;
    int tot2 = nj * ni * EDIM;
    for (int idx = threadIdx.x; idx < tot2; idx += 256) {
        int jj = idx / (ni*EDIM);
        int rem = idx - jj*(ni*EDIM);     // ii*5 + e
        int ii = rem / EDIM, e = rem - ii*EDIM;
        dst[(size_t)jj*R*EDIM + rem] = tile[ii][jj*EDIM + e];
    }
}

// ---------------- encode: h = relu([x, emb[gid]] @ W + b), 4 nodes/block ------
__global__ __launch_bounds__(256) void k_encode(
    const float* __restrict__ x, const float* __restrict__ emb,
    const int* __restrict__ group_ids,
    const float* __restrict__ W, const float* __restrict__ bvec,
    float* __restrict__ h) {
    int w = threadIdx.x >> 6, lane = threadIdx.x & 63;
    int n = blockIdx.x*4 + w;
    __shared__ float xin[4][136];
    for (int idx = lane; idx < INCH; idx += 64) xin[w][idx] = x[(size_t)n*INCH + idx];
    if (lane < EMBD) xin[w][INCH + lane] = emb[group_ids[n]*EMBD + lane];
    float acc = bvec[lane];
#pragma unroll
    for (int k = 0; k < INCH + EMBD; k += 4) {
        float4 q = *(const float4*)&xin[w][k];
        acc = fmaf(q.x, W[(k  )*HID + lane], acc);
        acc = fmaf(q.y, W[(k+1)*HID + lane], acc);
        acc = fmaf(q.z, W[(k+2)*HID + lane], acc);
        acc = fmaf(q.w, W[(k+3)*HID + lane], acc);
    }
    h[(size_t)n*HID + lane] = fmaxf(acc, 0.f);
}

// ---------------- batchnorm stats (two-stage, deterministic) ----------------
__global__ __launch_bounds__(256) void k_stats_partial(
    const float* __restrict__ h, float* __restrict__ partials) {
    int b = blockIdx.x;
    int tid = threadIdx.x;
    int c = tid & 63, r0 = tid >> 6;
    float s = 0.f, s2 = 0.f;
    int row0 = b*64;
#pragma unroll
    for (int k = 0; k < 16; ++k) {
        float v = h[(size_t)(row0 + r0 + 4*k)*HID + c];
        s += v; s2 += v*v;
    }
    __shared__ float ls[256], l2[256];
    ls[tid] = s; l2[tid] = s2;
    __syncthreads();
    if (tid < 64) {
        s  = ls[tid] + ls[tid+64] + ls[tid+128] + ls[tid+192];
        s2 = l2[tid] + l2[tid+64] + l2[tid+128] + l2[tid+192];
        partials[b*128 + tid]      = s;
        partials[b*128 + 64 + tid] = s2;
    }
}

__global__ __launch_bounds__(64) void k_stats_final(
    const float* __restrict__ partials, const float* __restrict__ gam,
    const float* __restrict__ bet, float* __restrict__ stats) {
    int c = threadIdx.x;
    float s = 0.f, s2 = 0.f;
    for (int b = 0; b < NN/64; ++b) {
        s  += partials[b*128 + c];
        s2 += partials[b*128 + 64 + c];
    }
    float mu  = s / (float)NN;
    float var = s2 / (float)NN - mu*mu;
    float rs  = rsqrtf(var + 1e-5f);
    float sc  = rs * gam[c];
    stats[c]      = sc;
    stats[64 + c] = bet[c] - mu*sc;
}

__global__ __launch_bounds__(256) void k_bn(
    float* __restrict__ h, const float* __restrict__ stats) {
    int i = blockIdx.x*256 + threadIdx.x;
    if (i < NN*HID) {
        int c = i & 63;
        h[i] = fmaf(h[i], stats[c], stats[64 + c]);
    }
}

// ---------------- GINE: wave per dst, transposed edge attrs ----------------
__global__ __launch_bounds__(256) void k_gine(
    const float* __restrict__ h, const float* __restrict__ eat,
    const float* __restrict__ We, const float* __restrict__ be,
    const float* __restrict__ W1, const float* __restrict__ b1,
    const float* __restrict__ W2, const float* __restrict__ b2,
    float* __restrict__ hout) {
    int b = blockIdx.x;
    int g = b / 29, chunk = b - g*29;
    int w = threadIdx.x >> 6, lane = threadIdx.x & 63;
    int j = chunk*4 + w;
    __shared__ float eac[4][R*8];      // 5 floats stored in 8-float slots
    __shared__ float t1s[4][68];
    const float* colp = eat + (size_t)(g*R + j)*R*EDIM;
    for (int idx = lane; idx < R*EDIM; idx += 64) {
        int i = idx / EDIM, e = idx - i*EDIM;
        eac[w][i*8 + e] = colp[idx];
    }
    float w0 = We[lane], w1v = We[64+lane], w2v = We[128+lane],
          w3v = We[192+lane], w4v = We[256+lane];
    float bec = be[lane];
    const float* hg = h + (size_t)g*R*HID;
    float agg = 0.f;
    for (int i = 0; i < R; ++i) {
        float4 q = *(const float4*)&eac[w][i*8];
        float q4 = eac[w][i*8 + 4];
        float ew = bec + q.x*w0 + q.y*w1v + q.z*w2v + q.w*w3v + q4*w4v;
        agg += fmaxf(hg[(size_t)i*HID + lane] + ew, 0.f);
    }
    float h1 = hg[(size_t)j*HID + lane] + agg;
    t1s[w][lane] = h1;
    float acc = b1[lane];
#pragma unroll
    for (int k = 0; k < HID; k += 4) {
        float4 tq = *(const float4*)&t1s[w][k];
        acc = fmaf(tq.x, W1[(k  )*HID + lane], acc);
        acc = fmaf(tq.y, W1[(k+1)*HID + lane], acc);
        acc = fmaf(tq.z, W1[(k+2)*HID + lane], acc);
        acc = fmaf(tq.w, W1[(k+3)*HID + lane], acc);
    }
    float t2 = fmaxf(acc, 0.f);
    t1s[w][lane] = t2;                 // same-wave in-order LDS
    float acc2 = b2[lane];
#pragma unroll
    for (int k = 0; k < HID; k += 4) {
        float4 tq = *(const float4*)&t1s[w][k];
        acc2 = fmaf(tq.x, W2[(k  )*HID + lane], acc2);
        acc2 = fmaf(tq.y, W2[(k+1)*HID + lane], acc2);
        acc2 = fmaf(tq.z, W2[(k+2)*HID + lane], acc2);
        acc2 = fmaf(tq.w, W2[(k+3)*HID + lane], acc2);
    }
    hout[(size_t)g*R*HID + (size_t)j*HID + lane] = fmaxf(acc2, 0.f);
}

// ---------------- GAT: xl/xr projections, 4 nodes/block ----------------
__global__ __launch_bounds__(256) void k_xlxr(
    const float* __restrict__ h,
    const float* __restrict__ Wl, const float* __restrict__ bl,
    const float* __restrict__ Wr, const float* __restrict__ br,
    float* __restrict__ xl, float* __restrict__ xr) {
    int w = threadIdx.x >> 6, lane = threadIdx.x & 63;
    int n = blockIdx.x*4 + w;
    __shared__ float hr[4][68];
    hr[w][lane] = h[(size_t)n*HID + lane];
    float aL = bl[lane], aR = br[lane];
#pragma unroll
    for (int k = 0; k < HID; k += 4) {
        float4 q = *(const float4*)&hr[w][k];
        aL = fmaf(q.x, Wl[(k  )*HID + lane], aL);
        aR = fmaf(q.x, Wr[(k  )*HID + lane], aR);
        aL = fmaf(q.y, Wl[(k+1)*HID + lane], aL);
        aR = fmaf(q.y, Wr[(k+1)*HID + lane], aR);
        aL = fmaf(q.z, Wl[(k+2)*HID + lane], aL);
        aR = fmaf(q.z, Wr[(k+2)*HID + lane], aR);
        aL = fmaf(q.w, Wl[(k+3)*HID + lane], aL);
        aR = fmaf(q.w, Wr[(k+3)*HID + lane], aR);
    }
    xl[(size_t)n*HID + lane] = aL;
    xr[(size_t)n*HID + lane] = aR;
}

// ---------------- GAT: wave per dst; lane=src scores, lane=ch agg ----------
__global__ __launch_bounds__(256) void k_gat(
    const float* __restrict__ xl, const float* __restrict__ xr,
    const float* __restrict__ eat, const float* __restrict__ We,
    const float* __restrict__ att, const float* __restrict__ bias,
    float* __restrict__ hout) {
    int b = blockIdx.x;
    int g = b / 29, chunk = b - g*29;
    int w = threadIdx.x >> 6, lane = threadIdx.x & 63;
    int j = chunk*4 + w;
    __shared__ float xls[128][65];     // rows 116..127 read-masked
    __shared__ float pp[4][64][8];     // per-wave: {We0..4[c], att[c], xr_j[c], 0}
    __shared__ float ps[4][120];
    __shared__ float bias_s[64];
    size_t hbase = (size_t)g*R*HID;
    for (int idx = threadIdx.x; idx < R*HID; idx += 256)
        xls[idx>>6][idx&63] = xl[hbase + idx];
    if (threadIdx.x < 64) bias_s[threadIdx.x] = bias[threadIdx.x];
    {   // build packed uniform table (lane = channel here)
        float g0 = We[lane], g1 = We[64+lane], g2 = We[128+lane],
              g3 = We[192+lane], g4 = We[256+lane];
        float at = att[lane];
        float u  = xr[hbase + (size_t)j*HID + lane];
        float4 A = {g0, g1, g2, g3};
        float4 B = {g4, at, u, 0.f};
        *(float4*)&pp[w][lane][0] = A;
        *(float4*)&pp[w][lane][4] = B;
    }
    __syncthreads();

    const float* colp = eat + (size_t)(g*R + j)*R*EDIM;
    float a0 = colp[lane*EDIM+0], a1 = colp[lane*EDIM+1], a2 = colp[lane*EDIM+2],
          a3 = colp[lane*EDIM+3], a4 = colp[lane*EDIM+4];
    bool vB = lane < (R - 64);
    float b0=0.f, b1v=0.f, b2v=0.f, b3v=0.f, b4v=0.f;
    if (vB) {
        const float* cb = colp + (size_t)(64 + lane)*EDIM;
        b0 = cb[0]; b1v = cb[1]; b2v = cb[2]; b3v = cb[3]; b4v = cb[4];
    }
    float accA = 0.f, accB = 0.f;
#pragma unroll 4
    for (int c = 0; c < HID; ++c) {
        float4 qa = *(const float4*)&pp[w][c][0];
        float4 qb = *(const float4*)&pp[w][c][4];
        float xA = xls[lane][c], xB = xls[64+lane][c];
        float zA = xA + qb.z + a0*qa.x + a1*qa.y + a2*qa.z + a3*qa.w + a4*qb.x;
        float zB = xB + qb.z + b0*qa.x + b1v*qa.y + b2v*qa.z + b3v*qa.w + b4v*qb.x;
        zA = fmaxf(zA, 0.f) + 0.2f*fminf(zA, 0.f);
        zB = fmaxf(zB, 0.f) + 0.2f*fminf(zB, 0.f);
        accA = fmaf(zA, qb.y, accA);
        accB = fmaf(zB, qb.y, accB);
    }
    float sA = accA, sB = vB ? accB : -1e30f;
    float m = fmaxf(sA, sB);
#pragma unroll
    for (int msk = 32; msk >= 1; msk >>= 1) m = fmaxf(m, __shfl_xor(m, msk, 64));
    float eA = __expf(sA - m);
    float eB = vB ? __expf(sB - m) : 0.f;
    float s = eA + eB;
#pragma unroll
    for (int msk = 32; msk >= 1; msk >>= 1) s += __shfl_xor(s, msk, 64);
    float inv = 1.f / (s + 1e-16f);
    ps[w][lane] = eA * inv;
    if (vB) ps[w][64 + lane] = eB * inv;
    // same-wave produce->consume
    float o = 0.f;
#pragma unroll 4
    for (int i = 0; i < R; i += 4) {
        float4 p4 = *(const float4*)&ps[w][i];
        o = fmaf(p4.x, xls[i  ][lane], o);
        o = fmaf(p4.y, xls[i+1][lane], o);
        o = fmaf(p4.z, xls[i+2][lane], o);
        o = fmaf(p4.w, xls[i+3][lane], o);
    }
    hout[hbase + (size_t)j*HID + lane] = fmaxf(o + bias_s[lane], 0.f);
}

// ---------------- pooling ----------------
__global__ __launch_bounds__(256) void k_pool_score(
    const float* __restrict__ h, const float* __restrict__ W1,
    const float* __restrict__ b1, const float* __restrict__ w2,
    float* __restrict__ scores) {
    int w = threadIdx.x >> 6, lane = threadIdx.x & 63;
    int n = blockIdx.x*4 + w;
    __shared__ float hr[4][68];
    hr[w][lane] = h[(size_t)n*HID + lane];
    float acc = b1[lane];
#pragma unroll
    for (int k = 0; k < HID; k += 4) {
        float4 q = *(const float4*)&hr[w][k];
        acc = fmaf(q.x, W1[(k  )*HID + lane], acc);
        acc = fmaf(q.y, W1[(k+1)*HID + lane], acc);
        acc = fmaf(q.z, W1[(k+2)*HID + lane], acc);
        acc = fmaf(q.w, W1[(k+3)*HID + lane], acc);
    }
    float p = tanhf(acc) * w2[lane];
    p = waveReduceSum(p);
    if (lane == 0) scores[n] = p;
}

__global__ __launch_bounds__(1024) void k_pool_reduce(
    const float* __restrict__ scores, float* __restrict__ ms) {
    __shared__ float red[1024];
    int tid = threadIdx.x;
    float m = -1e30f;
    for (int i = tid; i < NN; i += 1024) m = fmaxf(m, scores[i]);
    red[tid] = m;
    __syncthreads();
    for (int s = 512; s > 0; s >>= 1) {
        if (tid < s) red[tid] = fmaxf(red[tid], red[tid+s]);
        __syncthreads();
    }
    float mx = red[0];
    __syncthreads();
    float sum = 0.f;
    for (int i = tid; i < NN; i += 1024) sum += __expf(scores[i] - mx);
    red[tid] = sum;
    __syncthreads();
    for (int s = 512; s > 0; s >>= 1) {
        if (tid < s) red[tid] += red[tid+s];
        __syncthreads();
    }
    if (tid == 0) { ms[0] = mx; ms[1] = red[0]; }
}

__global__ __launch_bounds__(64) void k_pool_final(
    const float* __restrict__ h, const float* __restrict__ scores,
    const float* __restrict__ ms,
    const float* __restrict__ lin1W, const float* __restrict__ lin1b,
    const float* __restrict__ lin2W, const float* __restrict__ lin2b,
    float* __restrict__ out) {
    int g = blockIdx.x, c = threadIdx.x;
    float mx = ms[0], inv = 1.f / ms[1];
    float pc = 0.f;
    int nb = g*R;
    for (int r = 0; r < R; ++r) {
        float wv = __expf(scores[nb + r] - mx) * inv;
        pc = fmaf(h[(size_t)(nb + r)*HID + c], wv, pc);
    }
    __shared__ float pl[HID];
    __shared__ float t[INCH];
    pl[c] = pc;
    __syncthreads();
    for (int k = c; k < INCH; k += 64) {
        float acc = lin1b[k];
#pragma unroll 8
        for (int q = 0; q < HID; ++q) acc = fmaf(pl[q], lin1W[q*INCH + k], acc);
        t[k] = fmaxf(acc, 0.f);
    }
    __syncthreads();
    if (c < 2) {
        float o = lin2b[c];
        for (int k = 0; k < INCH; ++k) o = fmaf(t[k], lin2W[k*2 + c], o);
        out[g*2 + c] = o;
    }
}

extern "C" void kernel_launch(void* const* d_in, const int* in_sizes, int n_in,
                              void* d_out, int out_size, void* d_ws, size_t ws_size,
                              hipStream_t stream) {
    (void)in_sizes; (void)n_in; (void)out_size; (void)ws_size;
    const float* x        = (const float*)d_in[0];
    const float* edge_attr= (const float*)d_in[1];
    const float* emb      = (const float*)d_in[2];
    const float* enc_W    = (const float*)d_in[3];
    const float* enc_b    = (const float*)d_in[4];
    const float* bn_g     = (const float*)d_in[5];
    const float* bn_b     = (const float*)d_in[6];
    const float* gine_We  = (const float*)d_in[7];
    const float* gine_be  = (const float*)d_in[8];
    const float* gine_W1  = (const float*)d_in[9];
    const float* gine_b1  = (const float*)d_in[10];
    const float* gine_W2  = (const float*)d_in[11];
    const float* gine_b2  = (const float*)d_in[12];
    const float* gat_Wl   = (const float*)d_in[13];
    const float* gat_bl   = (const float*)d_in[14];
    const float* gat_Wr   = (const float*)d_in[15];
    const float* gat_br   = (const float*)d_in[16];
    const float* gat_att  = (const float*)d_in[17];
    const float* gat_We   = (const float*)d_in[18];
    const float* gat_bias = (const float*)d_in[19];
    const float* pool_W1  = (const float*)d_in[20];
    const float* pool_b1  = (const float*)d_in[21];
    const float* pool_w2  = (const float*)d_in[22];
    const float* lin1_W   = (const float*)d_in[23];
    const float* lin1_b   = (const float*)d_in[24];
    const float* lin2_W   = (const float*)d_in[25];
    const float* lin2_b   = (const float*)d_in[26];
    const int*   group_ids= (const int*)d_in[29];
    float* out = (float*)d_out;

    float* w = (float*)d_ws;
    float* eat      = w;                          // E*EDIM = 8,611,840
    float* hA       = eat + (size_t)R2*G*EDIM;    // NN*HID
    float* hB       = hA + NN*HID;
    float* xl       = hB + NN*HID;
    float* xr       = xl + NN*HID;
    float* scores   = xr + NN*HID;                // NN
    float* partials = scores + NN;                // (NN/64)*128
    float* stats    = partials + (NN/64)*128;     // 128
    float* pms      = stats + 128;                // 2

    k_etr<<<G*16, 256, 0, stream>>>(edge_attr, eat);
    k_encode<<<NN/4, 256, 0, stream>>>(x, emb, group_ids, enc_W, enc_b, hA);
    k_stats_partial<<<NN/64, 256, 0, stream>>>(hA, partials);
    k_stats_final<<<1, 64, 0, stream>>>(partials, bn_g, bn_b, stats);
    k_bn<<<(NN*HID + 255)/256, 256, 0, stream>>>(hA, stats);
    k_gine<<<G*29, 256, 0, stream>>>(hA, eat, gine_We, gine_be,
                                     gine_W1, gine_b1, gine_W2, gine_b2, hB);
    // GAT layer 0: hB -> hA
    k_xlxr<<<NN/4, 256, 0, stream>>>(hB, gat_Wl, gat_bl, gat_Wr, gat_br, xl, xr);
    k_gat<<<G*29, 256, 0, stream>>>(xl, xr, eat, gat_We, gat_att, gat_bias, hA);
    // GAT layer 1: hA -> hB
    k_xlxr<<<NN/4, 256, 0, stream>>>(hA, gat_Wl + HID*HID, gat_bl + HID,
                                     gat_Wr + HID*HID, gat_br + HID, xl, xr);
    k_gat<<<G*29, 256, 0, stream>>>(xl, xr, eat, gat_We + EDIM*HID,
                                    gat_att + HID, gat_bias + HID, hB);
    // pooling + head
    k_pool_score<<<NN/4, 256, 0, stream>>>(hB, pool_W1, pool_b1, pool_w2, scores);
    k_pool_reduce<<<1, 1024, 0, stream>>>(scores, pms);
    k_pool_final<<<G, 64, 0, stream>>>(hB, scores, pms, lin1_W, lin1_b,
                                       lin2_W, lin2_b, out);
}

// Round 5
// 266.246 us; speedup vs baseline: 2.6347x; 1.1712x over previous
//
#include <hip/hip_runtime.h>
#include <math.h>

#define R    116
#define R2   (116*116)
#define G    128
#define NN   (R*G)      // 14848 nodes
#define HID  64
#define EDIM 5
#define INCH 116
#define EMBD 16

__device__ __forceinline__ float waveReduceSum(float v) {
#pragma unroll
    for (int m = 32; m >= 1; m >>= 1) v += __shfl_xor(v, m, 64);
    return v;
}

// ---------------- edge-attr transpose: eat[g][j][i][e] = ea[g][i][j][e] -------
__global__ __launch_bounds__(256) void k_etr(
    const float* __restrict__ ea, float* __restrict__ eat) {
    int b = blockIdx.x;
    int g = b >> 4;
    int t = b & 15;
    int i0 = (t >> 2) << 5, j0 = (t & 3) << 5;
    int ni = min(32, R - i0), nj = min(32, R - j0);
    __shared__ float tile[32][165];
    const float* src = ea + ((size_t)(g*R + i0)*R + j0)*EDIM;
    int tot = ni * nj * EDIM;
    for (int idx = threadIdx.x; idx < tot; idx += 256) {
        int ii = idx / (nj*EDIM);
        int rem = idx - ii*(nj*EDIM);
        tile[ii][rem] = src[(size_t)ii*R*EDIM + rem];
    }
    __syncthreads();
    float* dst = eat + ((size_t)(g*R + j0)*R + i0)*EDIM;
    int tot2 = nj * ni * EDIM;
    for (int idx = threadIdx.x; idx < tot2; idx += 256) {
        int jj = idx / (ni*EDIM);
        int rem = idx - jj*(ni*EDIM);     // ii*5 + e
        int ii = rem / EDIM, e = rem - ii*EDIM;
        dst[(size_t)jj*R*EDIM + rem] = tile[ii][jj*EDIM + e];
    }
}

// ---------------- encode: h = relu([x, emb[gid]] @ W + b), 4 nodes/block ------
__global__ __launch_bounds__(256) void k_encode(
    const float* __restrict__ x, const float* __restrict__ emb,
    const int* __restrict__ group_ids,
    const float* __restrict__ W, const float* __restrict__ bvec,
    float* __restrict__ h) {
    int w = threadIdx.x >> 6, lane = threadIdx.x & 63;
    int n = blockIdx.x*4 + w;
    __shared__ float xin[4][136];
    for (int idx = lane; idx < INCH; idx += 64) xin[w][idx] = x[(size_t)n*INCH + idx];
    if (lane < EMBD) xin[w][INCH + lane] = emb[group_ids[n]*EMBD + lane];
    float acc = bvec[lane];
#pragma unroll
    for (int k = 0; k < INCH + EMBD; k += 4) {
        float4 q = *(const float4*)&xin[w][k];
        acc = fmaf(q.x, W[(k  )*HID + lane], acc);
        acc = fmaf(q.y, W[(k+1)*HID + lane], acc);
        acc = fmaf(q.z, W[(k+2)*HID + lane], acc);
        acc = fmaf(q.w, W[(k+3)*HID + lane], acc);
    }
    h[(size_t)n*HID + lane] = fmaxf(acc, 0.f);
}

// ---------------- batchnorm stats (two-stage, deterministic) ----------------
__global__ __launch_bounds__(256) void k_stats_partial(
    const float* __restrict__ h, float* __restrict__ partials) {
    int b = blockIdx.x;
    int tid = threadIdx.x;
    int c = tid & 63, r0 = tid >> 6;
    float s = 0.f, s2 = 0.f;
    int row0 = b*64;
#pragma unroll
    for (int k = 0; k < 16; ++k) {
        float v = h[(size_t)(row0 + r0 + 4*k)*HID + c];
        s += v; s2 += v*v;
    }
    __shared__ float ls[256], l2[256];
    ls[tid] = s; l2[tid] = s2;
    __syncthreads();
    if (tid < 64) {
        s  = ls[tid] + ls[tid+64] + ls[tid+128] + ls[tid+192];
        s2 = l2[tid] + l2[tid+64] + l2[tid+128] + l2[tid+192];
        partials[b*128 + tid]      = s;
        partials[b*128 + 64 + tid] = s2;
    }
}

__global__ __launch_bounds__(64) void k_stats_final(
    const float* __restrict__ partials, const float* __restrict__ gam,
    const float* __restrict__ bet, float* __restrict__ stats) {
    int c = threadIdx.x;
    float s = 0.f, s2 = 0.f;
    for (int b = 0; b < NN/64; ++b) {
        s  += partials[b*128 + c];
        s2 += partials[b*128 + 64 + c];
    }
    float mu  = s / (float)NN;
    float var = s2 / (float)NN - mu*mu;
    float rs  = rsqrtf(var + 1e-5f);
    float sc  = rs * gam[c];
    stats[c]      = sc;
    stats[64 + c] = bet[c] - mu*sc;
}

// ---------------- GINE: BN fused on load, panel staged once, 20 dsts/block ----
__global__ __launch_bounds__(256) void k_gine(
    const float* __restrict__ h, const float* __restrict__ stats,
    const float* __restrict__ eat,
    const float* __restrict__ We, const float* __restrict__ be,
    const float* __restrict__ W1, const float* __restrict__ b1,
    const float* __restrict__ W2, const float* __restrict__ b2,
    float* __restrict__ hout) {
    int b = blockIdx.x;
    int g = b & (G-1), chunk = b >> 7;     // 6 chunks of <=20 dsts
    int j0 = chunk*20, jcnt = min(20, R - j0);
    int tid = threadIdx.x, w = tid >> 6, lane = tid & 63;
    __shared__ float hs[R][64];
    __shared__ float eac[4][R*8];
    __shared__ float t1s[4][68];
    size_t hbase = (size_t)g*R*HID;
    float scv = stats[lane], shv = stats[64 + lane];
    for (int idx = tid; idx < R*HID; idx += 256)       // idx&63 == lane
        hs[idx>>6][lane] = fmaf(h[hbase + idx], scv, shv);
    float w0=We[lane], w1v=We[64+lane], w2v=We[128+lane],
          w3v=We[192+lane], w4v=We[256+lane], bec=be[lane];
    __syncthreads();
    for (int jj = w; jj < jcnt; jj += 4) {
        int j = j0 + jj;
        const float* colp = eat + (size_t)(g*R + j)*R*EDIM;
        for (int idx = lane; idx < R*EDIM; idx += 64) {
            int i = idx / EDIM, e = idx - i*EDIM;
            eac[w][i*8 + e] = colp[idx];
        }
        // same-wave produce->consume: no barrier
        float agg = 0.f;
        for (int i = 0; i < R; ++i) {
            float4 q = *(const float4*)&eac[w][i*8];
            float q4 = eac[w][i*8 + 4];
            float ew = bec;
            ew = fmaf(q.x, w0, ew); ew = fmaf(q.y, w1v, ew);
            ew = fmaf(q.z, w2v, ew); ew = fmaf(q.w, w3v, ew);
            ew = fmaf(q4, w4v, ew);
            agg += fmaxf(hs[i][lane] + ew, 0.f);
        }
        float h1 = hs[j][lane] + agg;
        t1s[w][lane] = h1;
        float acc = b1[lane];
#pragma unroll
        for (int k = 0; k < HID; k += 4) {
            float4 tq = *(const float4*)&t1s[w][k];
            acc = fmaf(tq.x, W1[(k  )*HID + lane], acc);
            acc = fmaf(tq.y, W1[(k+1)*HID + lane], acc);
            acc = fmaf(tq.z, W1[(k+2)*HID + lane], acc);
            acc = fmaf(tq.w, W1[(k+3)*HID + lane], acc);
        }
        float t2 = fmaxf(acc, 0.f);
        t1s[w][lane] = t2;
        float acc2 = b2[lane];
#pragma unroll
        for (int k = 0; k < HID; k += 4) {
            float4 tq = *(const float4*)&t1s[w][k];
            acc2 = fmaf(tq.x, W2[(k  )*HID + lane], acc2);
            acc2 = fmaf(tq.y, W2[(k+1)*HID + lane], acc2);
            acc2 = fmaf(tq.z, W2[(k+2)*HID + lane], acc2);
            acc2 = fmaf(tq.w, W2[(k+3)*HID + lane], acc2);
        }
        hout[hbase + (size_t)j*HID + lane] = fmaxf(acc2, 0.f);
    }
}

// ---------------- GAT: xl/xr projections + att-dot precompute ----------------
__global__ __launch_bounds__(256) void k_xlxr(
    const float* __restrict__ h,
    const float* __restrict__ Wl, const float* __restrict__ bl,
    const float* __restrict__ Wr, const float* __restrict__ br,
    const float* __restrict__ att,
    float* __restrict__ xl, float* __restrict__ xr,
    float* __restrict__ axl, float* __restrict__ axr) {
    int w = threadIdx.x >> 6, lane = threadIdx.x & 63;
    int n = blockIdx.x*4 + w;
    __shared__ float hr[4][68];
    hr[w][lane] = h[(size_t)n*HID + lane];
    float aL = bl[lane], aR = br[lane];
#pragma unroll
    for (int k = 0; k < HID; k += 4) {
        float4 q = *(const float4*)&hr[w][k];
        aL = fmaf(q.x, Wl[(k  )*HID + lane], aL);
        aR = fmaf(q.x, Wr[(k  )*HID + lane], aR);
        aL = fmaf(q.y, Wl[(k+1)*HID + lane], aL);
        aR = fmaf(q.y, Wr[(k+1)*HID + lane], aR);
        aL = fmaf(q.z, Wl[(k+2)*HID + lane], aL);
        aR = fmaf(q.z, Wr[(k+2)*HID + lane], aR);
        aL = fmaf(q.w, Wl[(k+3)*HID + lane], aL);
        aR = fmaf(q.w, Wr[(k+3)*HID + lane], aR);
    }
    xl[(size_t)n*HID + lane] = aL;
    xr[(size_t)n*HID + lane] = aR;
    float at = att[lane];
    float pL = waveReduceSum(aL * at);
    float pR = waveReduceSum(aR * at);
    if (lane == 0) { axl[n] = pL; axr[n] = pR; }
}

// ---------------- GAT: panel staged once, 15 dsts/block, abs-decomposed score -
__global__ __launch_bounds__(256) void k_gat(
    const float* __restrict__ xl, const float* __restrict__ xr,
    const float* __restrict__ axlg, const float* __restrict__ axrg,
    const float* __restrict__ eat, const float* __restrict__ We,
    const float* __restrict__ att, const float* __restrict__ bias,
    float* __restrict__ hout) {
    int b = blockIdx.x;
    int g = b & (G-1), chunk = b >> 7;     // 8 chunks of <=15 dsts
    int j0 = chunk*15, jcnt = min(15, R - j0);
    int tid = threadIdx.x, w = tid >> 6, lane = tid & 63;
    __shared__ float xls[R][65];
    __shared__ float we_s[64][8];          // {We0..4, att, 0, 0}
    __shared__ float xrs[15][64];
    __shared__ float axl_s[R];
    __shared__ float axr_s[16];
    __shared__ float ps[4][120];
    __shared__ float bias_s[64];
    __shared__ float was[8];               // We @ att
    size_t hbase = (size_t)g*R*HID;
    for (int idx = tid; idx < R*HID; idx += 256)
        xls[idx>>6][idx&63] = xl[hbase + idx];
    for (int idx = tid; idx < jcnt*HID; idx += 256)
        xrs[idx>>6][idx&63] = xr[hbase + (size_t)j0*HID + idx];
    if (tid < R) axl_s[tid] = axlg[g*R + tid];
    else if (tid < R + 16) {
        int q = tid - R;
        axr_s[q] = (q < jcnt) ? axrg[g*R + j0 + q] : 0.f;
    }
    if (tid >= 192) bias_s[tid - 192] = bias[tid - 192];
    if (w == 1) {
        float g0=We[lane], g1=We[64+lane], g2=We[128+lane],
              g3=We[192+lane], g4=We[256+lane], at=att[lane];
        we_s[lane][0]=g0; we_s[lane][1]=g1; we_s[lane][2]=g2; we_s[lane][3]=g3;
        we_s[lane][4]=g4; we_s[lane][5]=at; we_s[lane][6]=0.f; we_s[lane][7]=0.f;
        float p0 = waveReduceSum(g0*at);
        float p1 = waveReduceSum(g1*at);
        float p2 = waveReduceSum(g2*at);
        float p3 = waveReduceSum(g3*at);
        float p4 = waveReduceSum(g4*at);
        if (lane == 0) { was[0]=p0; was[1]=p1; was[2]=p2; was[3]=p3; was[4]=p4; }
    }
    __syncthreads();

    bool vB = lane < (R - 64);
    int rb = vB ? (64 + lane) : lane;      // clamped row keeps reads in-bounds
    for (int jj = w; jj < jcnt; jj += 4) {
        int j = j0 + jj;
        const float* colp = eat + (size_t)(g*R + j)*R*EDIM;
        const float* ca = colp + (size_t)lane*EDIM;
        float a0=ca[0], a1=ca[1], a2=ca[2], a3=ca[3], a4=ca[4];
        float b0=0.f, b1v=0.f, b2v=0.f, b3v=0.f, b4v=0.f;
        if (vB) {
            const float* cb = colp + (size_t)rb*EDIM;
            b0=cb[0]; b1v=cb[1]; b2v=cb[2]; b3v=cb[3]; b4v=cb[4];
        }
        float base = axr_s[jj];
        float LA = axl_s[lane] + base;
        LA = fmaf(a0,was[0],LA); LA = fmaf(a1,was[1],LA); LA = fmaf(a2,was[2],LA);
        LA = fmaf(a3,was[3],LA); LA = fmaf(a4,was[4],LA);
        float LB = axl_s[rb] + base;
        LB = fmaf(b0,was[0],LB); LB = fmaf(b1v,was[1],LB); LB = fmaf(b2v,was[2],LB);
        LB = fmaf(b3v,was[3],LB); LB = fmaf(b4v,was[4],LB);
        float accA = 0.f, accB = 0.f;
#pragma unroll 4
        for (int c = 0; c < HID; ++c) {
            float4 qa = *(const float4*)&we_s[c][0];
            float2 qb = *(const float2*)&we_s[c][4];
            float u  = xrs[jj][c];
            float zA = xls[lane][c] + u;
            zA = fmaf(a0,qa.x,zA); zA = fmaf(a1,qa.y,zA); zA = fmaf(a2,qa.z,zA);
            zA = fmaf(a3,qa.w,zA); zA = fmaf(a4,qb.x,zA);
            float zB = xls[rb][c] + u;
            zB = fmaf(b0,qa.x,zB); zB = fmaf(b1v,qa.y,zB); zB = fmaf(b2v,qa.z,zB);
            zB = fmaf(b3v,qa.w,zB); zB = fmaf(b4v,qb.x,zB);
            accA = fmaf(__builtin_fabsf(zA), qb.y, accA);
            accB = fmaf(__builtin_fabsf(zB), qb.y, accB);
        }
        // lrelu(z,0.2) = 0.6z + 0.4|z|  =>  score = 0.6*L + 0.4*acc
        float sA = fmaf(0.4f, accA, 0.6f*LA);
        float sB = vB ? fmaf(0.4f, accB, 0.6f*LB) : -1e30f;
        float m = fmaxf(sA, sB);
#pragma unroll
        for (int msk = 32; msk >= 1; msk >>= 1) m = fmaxf(m, __shfl_xor(m, msk, 64));
        float eA = __expf(sA - m);
        float eB = vB ? __expf(sB - m) : 0.f;
        float s = eA + eB;
#pragma unroll
        for (int msk = 32; msk >= 1; msk >>= 1) s += __shfl_xor(s, msk, 64);
        float inv = 1.f / (s + 1e-16f);
        ps[w][lane] = eA * inv;
        if (vB) ps[w][64 + lane] = eB * inv;
        // same-wave produce->consume
        float o = 0.f;
#pragma unroll 4
        for (int i = 0; i < R; i += 4) {
            float4 p4 = *(const float4*)&ps[w][i];
            o = fmaf(p4.x, xls[i  ][lane], o);
            o = fmaf(p4.y, xls[i+1][lane], o);
            o = fmaf(p4.z, xls[i+2][lane], o);
            o = fmaf(p4.w, xls[i+3][lane], o);
        }
        hout[hbase + (size_t)j*HID + lane] = fmaxf(o + bias_s[lane], 0.f);
    }
}

// ---------------- pooling ----------------
__global__ __launch_bounds__(256) void k_pool_score(
    const float* __restrict__ h, const float* __restrict__ W1,
    const float* __restrict__ b1, const float* __restrict__ w2,
    float* __restrict__ scores) {
    int w = threadIdx.x >> 6, lane = threadIdx.x & 63;
    int n = blockIdx.x*4 + w;
    __shared__ float hr[4][68];
    hr[w][lane] = h[(size_t)n*HID + lane];
    float acc = b1[lane];
#pragma unroll
    for (int k = 0; k < HID; k += 4) {
        float4 q = *(const float4*)&hr[w][k];
        acc = fmaf(q.x, W1[(k  )*HID + lane], acc);
        acc = fmaf(q.y, W1[(k+1)*HID + lane], acc);
        acc = fmaf(q.z, W1[(k+2)*HID + lane], acc);
        acc = fmaf(q.w, W1[(k+3)*HID + lane], acc);
    }
    float p = tanhf(acc) * w2[lane];
    p = waveReduceSum(p);
    if (lane == 0) scores[n] = p;
}

__global__ __launch_bounds__(1024) void k_pool_reduce(
    const float* __restrict__ scores, float* __restrict__ ms) {
    __shared__ float red[1024];
    int tid = threadIdx.x;
    float m = -1e30f;
    for (int i = tid; i < NN; i += 1024) m = fmaxf(m, scores[i]);
    red[tid] = m;
    __syncthreads();
    for (int s = 512; s > 0; s >>= 1) {
        if (tid < s) red[tid] = fmaxf(red[tid], red[tid+s]);
        __syncthreads();
    }
    float mx = red[0];
    __syncthreads();
    float sum = 0.f;
    for (int i = tid; i < NN; i += 1024) sum += __expf(scores[i] - mx);
    red[tid] = sum;
    __syncthreads();
    for (int s = 512; s > 0; s >>= 1) {
        if (tid < s) red[tid] += red[tid+s];
        __syncthreads();
    }
    if (tid == 0) { ms[0] = mx; ms[1] = red[0]; }
}

__global__ __launch_bounds__(64) void k_pool_final(
    const float* __restrict__ h, const float* __restrict__ scores,
    const float* __restrict__ ms,
    const float* __restrict__ lin1W, const float* __restrict__ lin1b,
    const float* __restrict__ lin2W, const float* __restrict__ lin2b,
    float* __restrict__ out) {
    int g = blockIdx.x, c = threadIdx.x;
    float mx = ms[0], inv = 1.f / ms[1];
    float pc = 0.f;
    int nb = g*R;
    for (int r = 0; r < R; ++r) {
        float wv = __expf(scores[nb + r] - mx) * inv;
        pc = fmaf(h[(size_t)(nb + r)*HID + c], wv, pc);
    }
    __shared__ float pl[HID];
    __shared__ float t[INCH];
    pl[c] = pc;
    __syncthreads();
    for (int k = c; k < INCH; k += 64) {
        float acc = lin1b[k];
#pragma unroll 8
        for (int q = 0; q < HID; ++q) acc = fmaf(pl[q], lin1W[q*INCH + k], acc);
        t[k] = fmaxf(acc, 0.f);
    }
    __syncthreads();
    if (c < 2) {
        float o = lin2b[c];
        for (int k = 0; k < INCH; ++k) o = fmaf(t[k], lin2W[k*2 + c], o);
        out[g*2 + c] = o;
    }
}

extern "C" void kernel_launch(void* const* d_in, const int* in_sizes, int n_in,
                              void* d_out, int out_size, void* d_ws, size_t ws_size,
                              hipStream_t stream) {
    (void)in_sizes; (void)n_in; (void)out_size; (void)ws_size;
    const float* x        = (const float*)d_in[0];
    const float* edge_attr= (const float*)d_in[1];
    const float* emb      = (const float*)d_in[2];
    const float* enc_W    = (const float*)d_in[3];
    const float* enc_b    = (const float*)d_in[4];
    const float* bn_g     = (const float*)d_in[5];
    const float* bn_b     = (const float*)d_in[6];
    const float* gine_We  = (const float*)d_in[7];
    const float* gine_be  = (const float*)d_in[8];
    const float* gine_W1  = (const float*)d_in[9];
    const float* gine_b1  = (const float*)d_in[10];
    const float* gine_W2  = (const float*)d_in[11];
    const float* gine_b2  = (const float*)d_in[12];
    const float* gat_Wl   = (const float*)d_in[13];
    const float* gat_bl   = (const float*)d_in[14];
    const float* gat_Wr   = (const float*)d_in[15];
    const float* gat_br   = (const float*)d_in[16];
    const float* gat_att  = (const float*)d_in[17];
    const float* gat_We   = (const float*)d_in[18];
    const float* gat_bias = (const float*)d_in[19];
    const float* pool_W1  = (const float*)d_in[20];
    const float* pool_b1  = (const float*)d_in[21];
    const float* pool_w2  = (const float*)d_in[22];
    const float* lin1_W   = (const float*)d_in[23];
    const float* lin1_b   = (const float*)d_in[24];
    const float* lin2_W   = (const float*)d_in[25];
    const float* lin2_b   = (const float*)d_in[26];
    const int*   group_ids= (const int*)d_in[29];
    float* out = (float*)d_out;

    float* w = (float*)d_ws;
    float* eat      = w;                            // R2*G*EDIM
    float* hA       = eat + (size_t)R2*G*EDIM;      // NN*HID
    float* hB       = hA + (size_t)NN*HID;
    float* xlb      = hB + (size_t)NN*HID;
    float* xrb      = xlb + (size_t)NN*HID;
    float* axl      = xrb + (size_t)NN*HID;         // NN
    float* axr      = axl + NN;                     // NN
    float* scores   = axr + NN;                     // NN
    float* partials = scores + NN;                  // 232*128
    float* stats    = partials + (NN/64)*128;       // 128
    float* pms      = stats + 128;                  // 2

    k_etr<<<G*16, 256, 0, stream>>>(edge_attr, eat);
    k_encode<<<NN/4, 256, 0, stream>>>(x, emb, group_ids, enc_W, enc_b, hA);
    k_stats_partial<<<NN/64, 256, 0, stream>>>(hA, partials);
    k_stats_final<<<1, 64, 0, stream>>>(partials, bn_g, bn_b, stats);
    k_gine<<<G*6, 256, 0, stream>>>(hA, stats, eat, gine_We, gine_be,
                                    gine_W1, gine_b1, gine_W2, gine_b2, hB);
    // GAT layer 0: hB -> hA
    k_xlxr<<<NN/4, 256, 0, stream>>>(hB, gat_Wl, gat_bl, gat_Wr, gat_br,
                                     gat_att, xlb, xrb, axl, axr);
    k_gat<<<G*8, 256, 0, stream>>>(xlb, xrb, axl, axr, eat, gat_We,
                                   gat_att, gat_bias, hA);
    // GAT layer 1: hA -> hB
    k_xlxr<<<NN/4, 256, 0, stream>>>(hA, gat_Wl + HID*HID, gat_bl + HID,
                                     gat_Wr + HID*HID, gat_br + HID,
                                     gat_att + HID, xlb, xrb, axl, axr);
    k_gat<<<G*8, 256, 0, stream>>>(xlb, xrb, axl, axr, eat, gat_We + EDIM*HID,
                                   gat_att + HID, gat_bias + HID, hB);
    // pooling + head
    k_pool_score<<<NN/4, 256, 0, stream>>>(hB, pool_W1, pool_b1, pool_w2, scores);
    k_pool_reduce<<<1, 1024, 0, stream>>>(scores, pms);
    k_pool_final<<<G, 64, 0, stream>>>(hB, scores, pms, lin1_W, lin1_b,
                                       lin2_W, lin2_b, out);
}